// Round 1
// baseline (271.689 us; speedup 1.0000x reference)
//
#include <hip/hip_runtime.h>
#include <stdint.h>

// Problem constants
#define Bsz 4096
#define Tn  64      // scan length (char_seq[:, :-1])
#define T1n 65
#define Hn  64
#define Pn  50
#define Vn  32

#define NW  5       // waves per block (4 scan + 1 proj/softmax)
#define NT  320     // threads per block

typedef __attribute__((ext_vector_type(8))) short short8;
typedef __attribute__((ext_vector_type(4))) float floatx4;

__device__ __forceinline__ float bf2f(unsigned short u) {
  union { unsigned int i; float f; } x; x.i = ((unsigned int)u) << 16; return x.f;
}
__device__ __forceinline__ unsigned short f2bf(float f) {
  union { float f; unsigned int i; } x; x.f = f;
  return (unsigned short)((x.i + 0x7FFFu + ((x.i >> 16) & 1u)) >> 16);
}
__device__ __forceinline__ float fast_sigmoid(float x) {
  return __builtin_amdgcn_rcpf(1.f + __expf(-x));
}
__device__ __forceinline__ float fast_tanh(float x) {
  return 1.f - 2.f * __builtin_amdgcn_rcpf(1.f + __expf(2.f * x));
}
// Barrier that drains LDS ops only (no vmcnt): global logit stores stay in
// flight across steps instead of being drained by __syncthreads' vmcnt(0).
__device__ __forceinline__ void bar_lgkm() {
  asm volatile("s_waitcnt lgkmcnt(0)\n\ts_barrier" ::: "memory");
}

// B-operand fragment for mfma_f32_16x16x32_bf16 from row-major (K x ncols) fp32 weights.
__device__ __forceinline__ short8 load_bfrag(const float* __restrict__ W, int ncols, int col, int kbase) {
  short8 f;
#pragma unroll
  for (int j = 0; j < 8; ++j) f[j] = (short)f2bf(W[(long)(kbase + j) * ncols + col]);
  return f;
}

// Fused GRU, R14: scan waves 0-3 own r AND z (two MFMA chains in interval A)
// exactly as R13. The logit-page + chunk-tail machinery is deleted: wave 4
// owns BOTH 16-col vocab tiles of W_proj, so it computes the full 16x32 logit
// tile of h_{t-1} in registers each step (interval A), stores logits straight
// to global, and finishes softmax+nll with 4 intra-16-lane shfl_xor in
// interval B. No logit LDS pages, no every-8-step tail burst, hist depth 2.
// Block = 320 threads (5 waves); main-loop barriers are lgkm-only.
__launch_bounds__(NT)
__global__ void gru_kernel(const float* __restrict__ phon,
                           const int* __restrict__ cs,
                           const float* __restrict__ emb,
                           const float* __restrict__ Wrx, const float* __restrict__ brx,
                           const float* __restrict__ Wrh, const float* __restrict__ brh,
                           const float* __restrict__ Wzx, const float* __restrict__ bzx,
                           const float* __restrict__ Wzh, const float* __restrict__ bzh,
                           const float* __restrict__ Whx, const float* __restrict__ bhx,
                           const float* __restrict__ Whh, const float* __restrict__ bhh,
                           const float* __restrict__ Wpj, const float* __restrict__ bpj_g,
                           float* __restrict__ ws,
                           float* __restrict__ outp) {
  __shared__ unsigned short tbl_s[3 * 32 * 66];             // bf16 [g][v][66]
  __shared__ __align__(16) unsigned short hist_s[2 * 1152]; // bf16 h[t&1][m][72]
  __shared__ __align__(16) unsigned short rh_s[1152];       // bf16 r*h [m][72]
  __shared__ unsigned int code4_s[(T1n + 1) * 4];           // packed codes [t][q]
  __shared__ int det_s[1];

  const int tid = threadIdx.x;
  const int b0 = blockIdx.x * 16;
  const int W8 = tid >> 6, lane = tid & 63, q = lane >> 4, c16 = lane & 15;
  const bool isScan = (W8 < 4);
  const int jcol = W8 * 16 + c16;   // scan waves only
  const floatx4 zf = {0.f, 0.f, 0.f, 0.f};

  // --- int32-vs-int64 detection for char_seq ---
  if (tid == 0) det_s[0] = 0;
  __syncthreads();
  if (tid < 128 && cs[2 * tid + 1] != 0) atomicOr(&det_s[0], 1);
  __syncthreads();
  const bool is64 = (det_s[0] == 0);

  // --- staging ---
  for (int i = tid; i < 1152; i += NT) hist_s[1152 + i] = 0;   // h0 slot (t=0 reads slot 1)
  for (int i = tid; i < T1n * 4; i += NT) {
    int t = i >> 2, qq = i & 3;
    unsigned int pk = 0;
#pragma unroll
    for (int r = 0; r < 4; ++r) {
      long idx = (long)(b0 + qq * 4 + r) * T1n + t;
      int c = is64 ? cs[2 * idx] : cs[idx];
      pk |= ((unsigned int)(c & 255)) << (8 * r);
    }
    code4_s[i] = pk;
  }

  // --- TBL: tbl_s[g][v][j] = bf16( emb[v] @ W_gx[:64] + b_gx[j] + b_gh[j] ) ---
  // 5 waves stride the 32 vocab slots: v = W8 + 5k.
  for (int g = 0; g < 3; ++g) {
    const float* Wg = (g == 0) ? Wrx : (g == 1) ? Wzx : Whx;
    const float* bx = (g == 0) ? brx : (g == 1) ? bzx : bhx;
    const float* bh = (g == 0) ? brh : (g == 1) ? bzh : bhh;
    float acc[7] = {0.f, 0.f, 0.f, 0.f, 0.f, 0.f, 0.f};
    float bias = bx[lane] + bh[lane];
    for (int d = 0; d < Hn; ++d) {
      float wv = Wg[(long)d * Hn + lane];
#pragma unroll
      for (int k = 0; k < 7; ++k) {
        int v = W8 + NW * k;
        if (v < 32) acc[k] += emb[(long)v * Hn + d] * wv;
      }
    }
#pragma unroll
    for (int k = 0; k < 7; ++k) {
      int v = W8 + NW * k;
      if (v < 32) tbl_s[g * 2112 + v * 66 + lane] = f2bf(acc[k] + bias);
    }
  }

  // --- PH per-lane (scan waves only): r, z, h gates ---
  float ph_r[4] = {0.f, 0.f, 0.f, 0.f};
  float ph_z[4] = {0.f, 0.f, 0.f, 0.f};
  float ph_h[4] = {0.f, 0.f, 0.f, 0.f};
  if (isScan) {
    for (int p = 0; p < Pn; ++p) {
      float wr = Wrx[(long)(Hn + p) * Hn + jcol];
      float wz = Wzx[(long)(Hn + p) * Hn + jcol];
      float wh = Whx[(long)(Hn + p) * Hn + jcol];
#pragma unroll
      for (int r = 0; r < 4; ++r) {
        float xv = phon[(long)(b0 + q * 4 + r) * Pn + p];
        ph_r[r] += xv * wr; ph_z[r] += xv * wz; ph_h[r] += xv * wh;
      }
    }
  }

  // --- B-fragments (register-resident, t-invariant) ---
  short8 Br0 = {0,0,0,0,0,0,0,0}, Br1 = Br0, Bz0 = Br0, Bz1 = Br0, Bh0 = Br0, Bh1 = Br0;
  short8 Bp00 = Br0, Bp01 = Br0, Bp10 = Br0, Bp11 = Br0;   // wave 4: W_proj both vocab tiles
  float bpj0 = 0.f, bpj1 = 0.f;
  if (isScan) {
    Br0 = load_bfrag(Wrh, Hn, jcol, q * 8);
    Br1 = load_bfrag(Wrh, Hn, jcol, 32 + q * 8);
    Bz0 = load_bfrag(Wzh, Hn, jcol, q * 8);
    Bz1 = load_bfrag(Wzh, Hn, jcol, 32 + q * 8);
    Bh0 = load_bfrag(Whh, Hn, jcol, q * 8);
    Bh1 = load_bfrag(Whh, Hn, jcol, 32 + q * 8);
  } else {
    Bp00 = load_bfrag(Wpj, Vn, c16,      q * 8);
    Bp01 = load_bfrag(Wpj, Vn, c16,      32 + q * 8);
    Bp10 = load_bfrag(Wpj, Vn, 16 + c16, q * 8);
    Bp11 = load_bfrag(Wpj, Vn, 16 + c16, 32 + q * 8);
    bpj0 = bpj_g[c16];
    bpj1 = bpj_g[16 + c16];
  }

  float h[4] = {0.f, 0.f, 0.f, 0.f};
  float z4[4] = {0.f, 0.f, 0.f, 0.f};
  float nll = 0.f, cnt = 0.f;

  __syncthreads();   // prologue done

  for (int t = 0; t < Tn; ++t) {
    const unsigned int pk = code4_s[t * 4 + q];
    unsigned short tc[4];                    // scan: c-gate TBL, prefetched A->B
    float lg0[4], lg1[4], e0[4], e1[4];      // wave 4: logits + exps, A->B

    // ===== interval A =====
    if (isScan) {
      const unsigned short* hp = &hist_s[((t + 1) & 1) * 1152];   // h_{t-1}
      short8 a0 = *(const short8*)&hp[c16 * 72 + q * 8];
      short8 a1 = *(const short8*)&hp[c16 * 72 + 32 + q * 8];
      floatx4 accr = __builtin_amdgcn_mfma_f32_16x16x32_bf16(a0, Br0, zf, 0, 0, 0);
      floatx4 accz = __builtin_amdgcn_mfma_f32_16x16x32_bf16(a0, Bz0, zf, 0, 0, 0);
      accr = __builtin_amdgcn_mfma_f32_16x16x32_bf16(a1, Br1, accr, 0, 0, 0);
      accz = __builtin_amdgcn_mfma_f32_16x16x32_bf16(a1, Bz1, accz, 0, 0, 0);
#pragma unroll
      for (int r = 0; r < 4; ++r) {
        int cr = (pk >> (8 * r)) & 255;
        tc[r] = tbl_s[2 * 2112 + cr * 66 + jcol];
        float xr = bf2f(tbl_s[0 * 2112 + cr * 66 + jcol]) + ph_r[r] + accr[r];
        float xz = bf2f(tbl_s[1 * 2112 + cr * 66 + jcol]) + ph_z[r] + accz[r];
        z4[r] = fast_sigmoid(xz);
        rh_s[(q * 4 + r) * 72 + jcol] = f2bf(fast_sigmoid(xr) * h[r]);
      }
    } else if (t > 0) {   // wave 4: proj h_{t-1}, full 16x32 tile in registers
      const unsigned short* hp = &hist_s[((t + 1) & 1) * 1152];
      short8 a0 = *(const short8*)&hp[c16 * 72 + q * 8];
      short8 a1 = *(const short8*)&hp[c16 * 72 + 32 + q * 8];
      floatx4 l0 = __builtin_amdgcn_mfma_f32_16x16x32_bf16(a0, Bp00, zf, 0, 0, 0);
      floatx4 l1 = __builtin_amdgcn_mfma_f32_16x16x32_bf16(a0, Bp10, zf, 0, 0, 0);
      l0 = __builtin_amdgcn_mfma_f32_16x16x32_bf16(a1, Bp01, l0, 0, 0, 0);
      l1 = __builtin_amdgcn_mfma_f32_16x16x32_bf16(a1, Bp11, l1, 0, 0, 0);
      const int p = t - 1;
#pragma unroll
      for (int r = 0; r < 4; ++r) {
        lg0[r] = l0[r] + bpj0;
        lg1[r] = l1[r] + bpj1;
        long ad = ((long)(b0 + q * 4 + r)) * ((long)Tn * Vn) + (long)p * Vn;
        outp[ad + c16]      = lg0[r];
        outp[ad + 16 + c16] = lg1[r];
        e0[r] = __expf(lg0[r]);
        e1[r] = __expf(lg1[r]);
      }
    }
    bar_lgkm();  // A

    // ===== interval B =====
    if (isScan) {       // c-gate + h-update -> hist_s[t&1]
      short8 p0 = *(const short8*)&rh_s[c16 * 72 + q * 8];
      short8 p1 = *(const short8*)&rh_s[c16 * 72 + 32 + q * 8];
      floatx4 acc = __builtin_amdgcn_mfma_f32_16x16x32_bf16(p0, Bh0, zf, 0, 0, 0);
      acc = __builtin_amdgcn_mfma_f32_16x16x32_bf16(p1, Bh1, acc, 0, 0, 0);
      unsigned short* hw = &hist_s[(t & 1) * 1152];
#pragma unroll
      for (int r = 0; r < 4; ++r) {
        float xh = bf2f(tc[r]) + ph_h[r] + acc[r];
        float c = fast_tanh(xh);
        float hn = fmaf(z4[r], c - h[r], h[r]);
        h[r] = hn;
        hw[(q * 4 + r) * 72 + jcol] = f2bf(hn);
      }
    } else if (t > 0) {  // wave 4: softmax rows live in 16-lane q-groups
#pragma unroll
      for (int r = 0; r < 4; ++r) {
        float s = e0[r] + e1[r];
        s += __shfl_xor(s, 1); s += __shfl_xor(s, 2);
        s += __shfl_xor(s, 4); s += __shfl_xor(s, 8);
        float lse = __logf(s);     // |logits| <= ~8, safe without max-sub
        int targ = (pk >> (8 * r)) & 255;
        if (targ != 0) {
          if (c16 == targ)           { nll += lse - lg0[r]; cnt += 1.f; }
          else if (c16 + 16 == targ) { nll += lse - lg1[r]; cnt += 1.f; }
        }
      }
    }
    bar_lgkm();  // B
  }

  // ===== epilogue: wave 4 projects + finalizes page 63 (h_63 in slot 1) =====
  if (W8 == 4) {
    const unsigned short* hp = &hist_s[1 * 1152];
    short8 a0 = *(const short8*)&hp[c16 * 72 + q * 8];
    short8 a1 = *(const short8*)&hp[c16 * 72 + 32 + q * 8];
    floatx4 l0 = __builtin_amdgcn_mfma_f32_16x16x32_bf16(a0, Bp00, zf, 0, 0, 0);
    floatx4 l1 = __builtin_amdgcn_mfma_f32_16x16x32_bf16(a0, Bp10, zf, 0, 0, 0);
    l0 = __builtin_amdgcn_mfma_f32_16x16x32_bf16(a1, Bp01, l0, 0, 0, 0);
    l1 = __builtin_amdgcn_mfma_f32_16x16x32_bf16(a1, Bp11, l1, 0, 0, 0);
    const unsigned int pk = code4_s[64 * 4 + q];
#pragma unroll
    for (int r = 0; r < 4; ++r) {
      float g0 = l0[r] + bpj0, g1 = l1[r] + bpj1;
      long ad = ((long)(b0 + q * 4 + r)) * ((long)Tn * Vn) + (long)63 * Vn;
      outp[ad + c16]      = g0;
      outp[ad + 16 + c16] = g1;
      float s = __expf(g0) + __expf(g1);
      s += __shfl_xor(s, 1); s += __shfl_xor(s, 2);
      s += __shfl_xor(s, 4); s += __shfl_xor(s, 8);
      float lse = __logf(s);
      int targ = (pk >> (8 * r)) & 255;
      if (targ != 0) {
        if (c16 == targ)           { nll += lse - g0; cnt += 1.f; }
        else if (c16 + 16 == targ) { nll += lse - g1; cnt += 1.f; }
      }
    }
    // ===== reduction -> per-block ws slot (wave 4 only holds nll) =====
#pragma unroll
    for (int off = 32; off >= 1; off >>= 1) {
      nll += __shfl_xor(nll, off);
      cnt += __shfl_xor(cnt, off);
    }
    if (lane == 0) {
      ws[2 * blockIdx.x] = nll;
      ws[2 * blockIdx.x + 1] = cnt;
    }
  }
}

__global__ void loss_kernel(const float* __restrict__ ws, float* __restrict__ outp) {
  int lane = threadIdx.x;  // 64 threads
  float n = 0.f, c = 0.f;
  for (int i = lane; i < Bsz / 16; i += 64) { n += ws[2 * i]; c += ws[2 * i + 1]; }
#pragma unroll
  for (int off = 32; off >= 1; off >>= 1) {
    n += __shfl_xor(n, off);
    c += __shfl_xor(c, off);
  }
  if (lane == 0) outp[(size_t)Bsz * Tn * Vn] = n / fmaxf(c, 1.f);
}

extern "C" void kernel_launch(void* const* d_in, const int* in_sizes, int n_in,
                              void* d_out, int out_size, void* d_ws, size_t ws_size,
                              hipStream_t stream) {
  const float* phon = (const float*)d_in[0];
  const int*   cs   = (const int*)d_in[1];
  const float* emb  = (const float*)d_in[2];
  const float* Wrx  = (const float*)d_in[3];
  const float* brx  = (const float*)d_in[4];
  const float* Wrh  = (const float*)d_in[5];
  const float* brh  = (const float*)d_in[6];
  const float* Wzx  = (const float*)d_in[7];
  const float* bzx  = (const float*)d_in[8];
  const float* Wzh  = (const float*)d_in[9];
  const float* bzh  = (const float*)d_in[10];
  const float* Whx  = (const float*)d_in[11];
  const float* bhx  = (const float*)d_in[12];
  const float* Whh  = (const float*)d_in[13];
  const float* bhh  = (const float*)d_in[14];
  const float* Wpj  = (const float*)d_in[15];
  const float* bpj  = (const float*)d_in[16];
  float* ws = (float*)d_ws;

  hipLaunchKernelGGL(gru_kernel, dim3(Bsz / 16), dim3(NT), 0, stream,
                     phon, cs, emb, Wrx, brx, Wrh, brh, Wzx, bzx, Wzh, bzh,
                     Whx, bhx, Whh, bhh, Wpj, bpj, ws, (float*)d_out);
  hipLaunchKernelGGL(loss_kernel, dim3(1), dim3(64), 0, stream, ws, (float*)d_out);
}